// Round 1
// baseline (1413.842 us; speedup 1.0000x reference)
//
#include <hip/hip_runtime.h>

#define NN 50000
#define EE 1600000
#define DD 128
#define NL 4
#define BN_EPS 1e-5f

// ---------------- CSR build ----------------

__global__ void k_count(const int* __restrict__ dst, int* __restrict__ counts, int E) {
  int e = blockIdx.x * blockDim.x + threadIdx.x;
  if (e < E) atomicAdd(&counts[dst[e]], 1);
}

__global__ void k_scan_tiles(const int* __restrict__ counts, int* __restrict__ row_start,
                             int* __restrict__ tile_sums, int n) {
  __shared__ int s[256];
  int t = threadIdx.x;
  int i = blockIdx.x * 256 + t;
  int v = (i < n) ? counts[i] : 0;
  s[t] = v;
  __syncthreads();
  for (int off = 1; off < 256; off <<= 1) {
    int x = (t >= off) ? s[t - off] : 0;
    __syncthreads();
    s[t] += x;
    __syncthreads();
  }
  if (i < n) row_start[i] = s[t] - v;  // exclusive within tile
  if (t == 255) tile_sums[blockIdx.x] = s[255];
}

__global__ void k_scan_sums(int* __restrict__ tile_sums, int ntiles) {
  __shared__ int s[256];
  int t = threadIdx.x;
  int v = (t < ntiles) ? tile_sums[t] : 0;
  s[t] = v;
  __syncthreads();
  for (int off = 1; off < 256; off <<= 1) {
    int x = (t >= off) ? s[t - off] : 0;
    __syncthreads();
    s[t] += x;
    __syncthreads();
  }
  if (t < ntiles) tile_sums[t] = s[t] - v;  // exclusive scan of tile totals
}

__global__ void k_scan_add(int* __restrict__ row_start, const int* __restrict__ tile_sums,
                           int n, int E) {
  int i = blockIdx.x * blockDim.x + threadIdx.x;
  if (i < n) row_start[i] += tile_sums[i >> 8];
  if (i == 0) row_start[n] = E;
}

__global__ void k_fill(const int* __restrict__ src, const int* __restrict__ dst,
                       const int* __restrict__ row_start, int* __restrict__ counts,
                       int* __restrict__ perm, int E) {
  int e = blockIdx.x * blockDim.x + threadIdx.x;
  if (e < E) {
    int d = dst[e];
    int pos = row_start[d] + atomicSub(&counts[d], 1) - 1;
    perm[pos] = src[e];
  }
}

// ---------------- GIN aggregation (pull, CSR) ----------------
// one wave per node; halves of the wave take alternate edges; float4 per lane

__global__ __launch_bounds__(256) void k_aggregate(
    const float* __restrict__ h, const int* __restrict__ row_start,
    const int* __restrict__ perm, const float* __restrict__ epsv, int layer,
    float* __restrict__ xout, int n) {
  int wv = (blockIdx.x * 256 + threadIdx.x) >> 6;
  if (wv >= n) return;
  int lane = threadIdx.x & 63;
  int chunk = lane & 31;
  int half = lane >> 5;
  int beg = row_start[wv], end = row_start[wv + 1];
  float4 acc = make_float4(0.f, 0.f, 0.f, 0.f);
  for (int e = beg + half; e < end; e += 2) {
    int s = perm[e];
    float4 v = ((const float4*)(h + (size_t)s * DD))[chunk];
    acc.x += v.x; acc.y += v.y; acc.z += v.z; acc.w += v.w;
  }
  acc.x += __shfl_xor(acc.x, 32);
  acc.y += __shfl_xor(acc.y, 32);
  acc.z += __shfl_xor(acc.z, 32);
  acc.w += __shfl_xor(acc.w, 32);
  if (half == 0) {
    float ep = 1.0f + epsv[layer];
    float4 hv = ((const float4*)(h + (size_t)wv * DD))[chunk];
    float4 o;
    o.x = fmaf(ep, hv.x, acc.x);
    o.y = fmaf(ep, hv.y, acc.y);
    o.z = fmaf(ep, hv.z, acc.z);
    o.w = fmaf(ep, hv.w, acc.w);
    ((float4*)(xout + (size_t)wv * DD))[chunk] = o;
  }
}

// ---------------- fp32 GEMM [nrows,128] x [128,128] + bias ----------------
// PRE: apply relu(x*scale+shift) elementwise on load (BN+relu of previous stage)
// STATS: accumulate column sum / sumsq of the OUTPUT into stats[0..127], stats[128..255]

template <bool PRE, bool STATS>
__global__ __launch_bounds__(256) void k_gemm(
    const float* __restrict__ X, const float* __restrict__ Wm,
    const float* __restrict__ bias, const float* __restrict__ scale,
    const float* __restrict__ shift, float* __restrict__ Y,
    float* __restrict__ stats, int nrows) {
  __shared__ float sX[64][DD + 1];
  __shared__ float red[2][DD];
  int tid = threadIdx.x;
  int rowBase = blockIdx.x * 64;

  if (STATS) {
    if (tid < DD) { red[0][tid] = 0.f; red[1][tid] = 0.f; }
  }

#pragma unroll
  for (int j = 0; j < 8; ++j) {
    int f4 = tid + 256 * j;
    int r = f4 >> 5;
    int c4 = f4 & 31;
    int row = rowBase + r;
    float4 v = make_float4(0.f, 0.f, 0.f, 0.f);
    if (row < nrows) v = ((const float4*)(X + (size_t)row * DD))[c4];
    if (PRE) {
      float4 sc = ((const float4*)scale)[c4];
      float4 sh = ((const float4*)shift)[c4];
      v.x = fmaxf(fmaf(v.x, sc.x, sh.x), 0.f);
      v.y = fmaxf(fmaf(v.y, sc.y, sh.y), 0.f);
      v.z = fmaxf(fmaf(v.z, sc.z, sh.z), 0.f);
      v.w = fmaxf(fmaf(v.w, sc.w, sh.w), 0.f);
    }
    sX[r][c4 * 4 + 0] = v.x;
    sX[r][c4 * 4 + 1] = v.y;
    sX[r][c4 * 4 + 2] = v.z;
    sX[r][c4 * 4 + 3] = v.w;
  }
  __syncthreads();

  int c = tid & 31;   // float4 column index
  int rg = tid >> 5;  // row group 0..7, 8 rows each
  float4 bv = ((const float4*)bias)[c];
  float4 acc[8];
#pragma unroll
  for (int i = 0; i < 8; ++i) acc[i] = bv;

  const float4* W4 = (const float4*)Wm;
#pragma unroll 4
  for (int k = 0; k < DD; ++k) {
    float4 w = W4[k * 32 + c];
#pragma unroll
    for (int i = 0; i < 8; ++i) {
      float xv = sX[rg * 8 + i][k];
      acc[i].x = fmaf(xv, w.x, acc[i].x);
      acc[i].y = fmaf(xv, w.y, acc[i].y);
      acc[i].z = fmaf(xv, w.z, acc[i].z);
      acc[i].w = fmaf(xv, w.w, acc[i].w);
    }
  }

#pragma unroll
  for (int i = 0; i < 8; ++i) {
    int row = rowBase + rg * 8 + i;
    if (row < nrows) ((float4*)(Y + (size_t)row * DD))[c] = acc[i];
  }

  if (STATS) {
    float4 s = make_float4(0.f, 0.f, 0.f, 0.f);
    float4 q = make_float4(0.f, 0.f, 0.f, 0.f);
#pragma unroll
    for (int i = 0; i < 8; ++i) {
      int row = rowBase + rg * 8 + i;
      if (row < nrows) {
        s.x += acc[i].x; q.x += acc[i].x * acc[i].x;
        s.y += acc[i].y; q.y += acc[i].y * acc[i].y;
        s.z += acc[i].z; q.z += acc[i].z * acc[i].z;
        s.w += acc[i].w; q.w += acc[i].w * acc[i].w;
      }
    }
    atomicAdd(&red[0][c * 4 + 0], s.x);
    atomicAdd(&red[0][c * 4 + 1], s.y);
    atomicAdd(&red[0][c * 4 + 2], s.z);
    atomicAdd(&red[0][c * 4 + 3], s.w);
    atomicAdd(&red[1][c * 4 + 0], q.x);
    atomicAdd(&red[1][c * 4 + 1], q.y);
    atomicAdd(&red[1][c * 4 + 2], q.z);
    atomicAdd(&red[1][c * 4 + 3], q.w);
    __syncthreads();
    if (tid < DD) {
      atomicAdd(&stats[tid], red[0][tid]);
      atomicAdd(&stats[DD + tid], red[1][tid]);
    }
  }
}

// ---------------- BN finalize: scale/shift from stats; zero stats for next use ----

__global__ void k_bnfin(const float* __restrict__ stats, const float* __restrict__ gamma,
                        const float* __restrict__ beta, float* __restrict__ scale,
                        float* __restrict__ shift, float* __restrict__ statsz, float inv_n) {
  int d = threadIdx.x;
  if (d < DD) {
    float mu = stats[d] * inv_n;
    float var = stats[DD + d] * inv_n - mu * mu;
    float sc = gamma[d] * rsqrtf(var + BN_EPS);
    scale[d] = sc;
    shift[d] = fmaf(-mu, sc, beta[d]);
    statsz[d] = 0.f;
    statsz[DD + d] = 0.f;
  }
}

// ---------------- stats of a = relu(bn2(z)) ----------------

__global__ __launch_bounds__(256) void k_stats3(const float* __restrict__ Z,
                                                const float* __restrict__ sc2,
                                                const float* __restrict__ sh2,
                                                float* __restrict__ stats, int n4) {
  __shared__ float red[2][DD];
  int tid = threadIdx.x;
  if (tid < DD) { red[0][tid] = 0.f; red[1][tid] = 0.f; }
  __syncthreads();
  int c4 = tid & 31;
  float4 sc = ((const float4*)sc2)[c4];
  float4 sh = ((const float4*)sh2)[c4];
  float4 s = make_float4(0.f, 0.f, 0.f, 0.f);
  float4 q = make_float4(0.f, 0.f, 0.f, 0.f);
  for (int idx = blockIdx.x * 256 + tid; idx < n4; idx += gridDim.x * 256) {
    float4 z = ((const float4*)Z)[idx];
    float a;
    a = fmaxf(fmaf(z.x, sc.x, sh.x), 0.f); s.x += a; q.x += a * a;
    a = fmaxf(fmaf(z.y, sc.y, sh.y), 0.f); s.y += a; q.y += a * a;
    a = fmaxf(fmaf(z.z, sc.z, sh.z), 0.f); s.z += a; q.z += a * a;
    a = fmaxf(fmaf(z.w, sc.w, sh.w), 0.f); s.w += a; q.w += a * a;
  }
  atomicAdd(&red[0][c4 * 4 + 0], s.x);
  atomicAdd(&red[0][c4 * 4 + 1], s.y);
  atomicAdd(&red[0][c4 * 4 + 2], s.z);
  atomicAdd(&red[0][c4 * 4 + 3], s.w);
  atomicAdd(&red[1][c4 * 4 + 0], q.x);
  atomicAdd(&red[1][c4 * 4 + 1], q.y);
  atomicAdd(&red[1][c4 * 4 + 2], q.z);
  atomicAdd(&red[1][c4 * 4 + 3], q.w);
  __syncthreads();
  if (tid < DD) {
    atomicAdd(&stats[tid], red[0][tid]);
    atomicAdd(&stats[DD + tid], red[1][tid]);
  }
}

// ---------------- final: h_out = h_in + relu(bn3(relu(bn2(z)))) ----------------

__global__ __launch_bounds__(256) void k_final(const float* __restrict__ Z,
                                               const float* __restrict__ Hin,
                                               const float* __restrict__ sc2,
                                               const float* __restrict__ sh2,
                                               const float* __restrict__ sc3,
                                               const float* __restrict__ sh3,
                                               float* __restrict__ Hout, int n4) {
  int c4 = threadIdx.x & 31;
  float4 s2 = ((const float4*)sc2)[c4];
  float4 h2 = ((const float4*)sh2)[c4];
  float4 s3 = ((const float4*)sc3)[c4];
  float4 h3 = ((const float4*)sh3)[c4];
  for (int idx = blockIdx.x * 256 + threadIdx.x; idx < n4; idx += gridDim.x * 256) {
    float4 z = ((const float4*)Z)[idx];
    float4 hv = ((const float4*)Hin)[idx];
    float4 o;
    float a;
    a = fmaxf(fmaf(z.x, s2.x, h2.x), 0.f);
    o.x = hv.x + fmaxf(fmaf(a, s3.x, h3.x), 0.f);
    a = fmaxf(fmaf(z.y, s2.y, h2.y), 0.f);
    o.y = hv.y + fmaxf(fmaf(a, s3.y, h3.y), 0.f);
    a = fmaxf(fmaf(z.z, s2.z, h2.z), 0.f);
    o.z = hv.z + fmaxf(fmaf(a, s3.z, h3.z), 0.f);
    a = fmaxf(fmaf(z.w, s2.w, h2.w), 0.f);
    o.w = hv.w + fmaxf(fmaf(a, s3.w, h3.w), 0.f);
    ((float4*)Hout)[idx] = o;
  }
}

// ---------------- launch ----------------

extern "C" void kernel_launch(void* const* d_in, const int* in_sizes, int n_in,
                              void* d_out, int out_size, void* d_ws, size_t ws_size,
                              hipStream_t stream) {
  const float* h_in = (const float*)d_in[0];
  const int* src = (const int*)d_in[1];
  const int* dst = (const int*)d_in[2];
  const float* W_emb = (const float*)d_in[3];
  const float* b_emb = (const float*)d_in[4];
  const float* epsv = (const float*)d_in[5];
  const float* W1 = (const float*)d_in[6];
  const float* b1 = (const float*)d_in[7];
  const float* g1 = (const float*)d_in[8];
  const float* be1 = (const float*)d_in[9];
  const float* W2 = (const float*)d_in[10];
  const float* b2 = (const float*)d_in[11];
  const float* ga = (const float*)d_in[12];
  const float* ba = (const float*)d_in[13];
  const float* gl = (const float*)d_in[14];
  const float* bl = (const float*)d_in[15];

  const int Nn = in_sizes[0] / DD;  // 50000
  const int E = in_sizes[1];        // 1600000

  char* ws = (char*)d_ws;
  size_t off = 0;
  auto alloc = [&](size_t bytes) -> void* {
    off = (off + 255) & ~(size_t)255;
    void* p = ws + off;
    off += bytes;
    return p;
  };
  float* bufA = (float*)alloc((size_t)Nn * DD * 4);
  float* bufB = (float*)alloc((size_t)Nn * DD * 4);
  float* bufC = (float*)d_out;  // y-scratch; overwritten by final output at the end
  int* perm = (int*)alloc((size_t)E * 4);
  int* row_start = (int*)alloc((size_t)(Nn + 1) * 4);
  int* counts = (int*)alloc((size_t)Nn * 4);
  int* tile_sums = (int*)alloc(256 * 4);
  float* S = (float*)alloc(2 * DD * 4);
  float* scale1 = (float*)alloc(DD * 4);
  float* shift1 = (float*)alloc(DD * 4);
  float* scale2 = (float*)alloc(DD * 4);
  float* shift2 = (float*)alloc(DD * 4);
  float* scale3 = (float*)alloc(DD * 4);
  float* shift3 = (float*)alloc(DD * 4);

  hipMemsetAsync(counts, 0, (size_t)Nn * 4, stream);
  hipMemsetAsync(S, 0, 2 * DD * 4, stream);

  int eb = (E + 255) / 256;
  int ntiles = (Nn + 255) / 256;
  k_count<<<eb, 256, 0, stream>>>(dst, counts, E);
  k_scan_tiles<<<ntiles, 256, 0, stream>>>(counts, row_start, tile_sums, Nn);
  k_scan_sums<<<1, 256, 0, stream>>>(tile_sums, ntiles);
  k_scan_add<<<ntiles, 256, 0, stream>>>(row_start, tile_sums, Nn, E);
  k_fill<<<eb, 256, 0, stream>>>(src, dst, row_start, counts, perm, E);

  int gb = (Nn + 63) / 64;
  // embed: h = h_in @ W_emb + b_emb
  k_gemm<false, false><<<gb, 256, 0, stream>>>(h_in, W_emb, b_emb, nullptr, nullptr,
                                               bufA, nullptr, Nn);

  int n4 = Nn * DD / 4;
  float inv_n = 1.0f / (float)Nn;
  float* h = bufA;
  for (int i = 0; i < NL; ++i) {
    float* x = (i & 1) ? bufA : bufB;  // also reused as z and (except last layer) h_out
    k_aggregate<<<(Nn + 3) / 4, 256, 0, stream>>>(h, row_start, perm, epsv, i, x, Nn);
    k_gemm<false, true><<<gb, 256, 0, stream>>>(x, W1 + (size_t)i * DD * DD, b1 + i * DD,
                                                nullptr, nullptr, bufC, S, Nn);
    k_bnfin<<<1, DD, 0, stream>>>(S, g1 + i * DD, be1 + i * DD, scale1, shift1, S, inv_n);
    k_gemm<true, true><<<gb, 256, 0, stream>>>(bufC, W2 + (size_t)i * DD * DD, b2 + i * DD,
                                               scale1, shift1, x, S, Nn);
    k_bnfin<<<1, DD, 0, stream>>>(S, ga + i * DD, ba + i * DD, scale2, shift2, S, inv_n);
    k_stats3<<<2048, 256, 0, stream>>>(x, scale2, shift2, S, n4);
    k_bnfin<<<1, DD, 0, stream>>>(S, gl + i * DD, bl + i * DD, scale3, shift3, S, inv_n);
    float* hout = (i == NL - 1) ? (float*)d_out : x;
    k_final<<<4096, 256, 0, stream>>>(x, h, scale2, shift2, scale3, shift3, hout, n4);
    h = hout;
  }
}

// Round 4
// 1111.563 us; speedup vs baseline: 1.2719x; 1.2719x over previous
//
#include <hip/hip_runtime.h>

#define DD 128
#define NL 4
#define BN_EPS 1e-5f
#define WSTRIDE 16384  // 128*128 bf16 elements per packed matrix

typedef __attribute__((ext_vector_type(8))) short short8;
typedef __attribute__((ext_vector_type(4))) float f32x4;

__device__ inline float bf2f(unsigned short u) {
  unsigned int x = ((unsigned int)u) << 16;
  return __builtin_bit_cast(float, x);
}
__device__ inline unsigned short f2bf(float f) {
  unsigned int u = __builtin_bit_cast(unsigned int, f);
  unsigned int r = (u + 0x7fffu + ((u >> 16) & 1u)) >> 16;
  return (unsigned short)r;
}

// ---------------- CSR build ----------------

__global__ void k_count(const int* __restrict__ dst, int* __restrict__ counts, int E) {
  int e = blockIdx.x * blockDim.x + threadIdx.x;
  if (e < E) atomicAdd(&counts[dst[e]], 1);
}

__global__ void k_scan_tiles(const int* __restrict__ counts, int* __restrict__ row_start,
                             int* __restrict__ tile_sums, int n) {
  __shared__ int s[256];
  int t = threadIdx.x;
  int i = blockIdx.x * 256 + t;
  int v = (i < n) ? counts[i] : 0;
  s[t] = v;
  __syncthreads();
  for (int off = 1; off < 256; off <<= 1) {
    int x = (t >= off) ? s[t - off] : 0;
    __syncthreads();
    s[t] += x;
    __syncthreads();
  }
  if (i < n) row_start[i] = s[t] - v;
  if (t == 255) tile_sums[blockIdx.x] = s[255];
}

__global__ void k_scan_sums(int* __restrict__ tile_sums, int ntiles) {
  __shared__ int s[256];
  int t = threadIdx.x;
  int v = (t < ntiles) ? tile_sums[t] : 0;
  s[t] = v;
  __syncthreads();
  for (int off = 1; off < 256; off <<= 1) {
    int x = (t >= off) ? s[t - off] : 0;
    __syncthreads();
    s[t] += x;
    __syncthreads();
  }
  if (t < ntiles) tile_sums[t] = s[t] - v;
}

__global__ void k_scan_add(int* __restrict__ row_start, const int* __restrict__ tile_sums,
                           int n, int E) {
  int i = blockIdx.x * blockDim.x + threadIdx.x;
  if (i < n) row_start[i] += tile_sums[i >> 8];
  if (i == 0) row_start[n] = E;
}

__global__ void k_fill(const int* __restrict__ src, const int* __restrict__ dst,
                       const int* __restrict__ row_start, int* __restrict__ counts,
                       int* __restrict__ perm, int E) {
  int e = blockIdx.x * blockDim.x + threadIdx.x;
  if (e < E) {
    int d = dst[e];
    int pos = row_start[d] + atomicSub(&counts[d], 1) - 1;
    perm[pos] = src[e];
  }
}

// ---------------- W pre-pack: fp32 [nmat,128,128] -> bf16 B-fragment order ------
// 32 fragments/matrix: frag=(t*4+s), t=0..7 (n-tile), s=0..3 (k-step).
// lane l, elem j holds W[k = s*32 + (l>>4)*8 + j][n = t*16 + (l&15)]

__global__ void k_packW(const float* __restrict__ W, unsigned short* __restrict__ out,
                        int nmat) {
  int idx = blockIdx.x * 256 + threadIdx.x;
  int m = idx >> 14;
  if (m >= nmat) return;
  int o = idx & (WSTRIDE - 1);
  int frag = o >> 9;         // 0..31
  int l = (o >> 3) & 63;
  int j = o & 7;
  int t = frag >> 2, s = frag & 3;
  int k = s * 32 + ((l >> 4) << 3) + j;
  int n = (t << 4) + (l & 15);
  out[(size_t)m * WSTRIDE + o] = f2bf(W[(size_t)m * (DD * DD) + k * DD + n]);
}

// ---------------- GIN aggregation (pull, CSR, bf16 rows) ----------------

__global__ __launch_bounds__(256) void k_aggregate(
    const unsigned short* __restrict__ hb, const int* __restrict__ row_start,
    const int* __restrict__ perm, const float* __restrict__ epsv, int layer,
    unsigned short* __restrict__ xout, int n) {
  int wv = (blockIdx.x * 256 + threadIdx.x) >> 6;
  if (wv >= n) return;
  int lane = threadIdx.x & 63;
  int sub = lane >> 4;   // which of 4 concurrent edges
  int c8 = lane & 15;    // which 8-col chunk of the row
  int beg = row_start[wv], end = row_start[wv + 1];
  float acc[8] = {0.f, 0.f, 0.f, 0.f, 0.f, 0.f, 0.f, 0.f};
  for (int e = beg + sub; e < end; e += 4) {
    int s = perm[e];
    short8 v = *(const short8*)(hb + (size_t)s * DD + c8 * 8);
#pragma unroll
    for (int j = 0; j < 8; ++j) acc[j] += bf2f((unsigned short)v[j]);
  }
#pragma unroll
  for (int j = 0; j < 8; ++j) {
    acc[j] += __shfl_xor(acc[j], 16);
    acc[j] += __shfl_xor(acc[j], 32);
  }
  if (sub == 0) {
    float ep = 1.0f + epsv[layer];
    short8 hv = *(const short8*)(hb + (size_t)wv * DD + c8 * 8);
    short8 o;
#pragma unroll
    for (int j = 0; j < 8; ++j)
      o[j] = (short)f2bf(fmaf(ep, bf2f((unsigned short)hv[j]), acc[j]));
    *(short8*)(xout + (size_t)wv * DD + c8 * 8) = o;
  }
}

// ---------------- bf16 MFMA GEMM [nrows,128] x [128,128] + bias ----------------

template <bool PRE, bool STATS, bool IN_F32, bool OUT_BF16, bool OUT_F32>
__global__ __launch_bounds__(256) void k_gemm_mfma(
    const void* __restrict__ Xv, const unsigned short* __restrict__ Wb,
    const float* __restrict__ bias, const float* __restrict__ scale,
    const float* __restrict__ shift, unsigned short* __restrict__ Yb,
    float* __restrict__ Yf, float* __restrict__ stats, int nrows) {
  __shared__ float red[2][DD];
  int tid = threadIdx.x;
  int wave = tid >> 6, lane = tid & 63;
  int quad = lane >> 4, n16 = lane & 15;
  int m0 = blockIdx.x * 64 + wave * 16;
  int rowA = m0 + n16;

  if (STATS) {
    if (tid < DD) { red[0][tid] = 0.f; red[1][tid] = 0.f; }
    __syncthreads();
  }

  f32x4 acc[8];
#pragma unroll
  for (int t = 0; t < 8; ++t) acc[t] = (f32x4){0.f, 0.f, 0.f, 0.f};

  const short8* W8 = (const short8*)Wb;
#pragma unroll
  for (int s = 0; s < 4; ++s) {
    int kbase = s * 32 + quad * 8;
    short8 a = {0, 0, 0, 0, 0, 0, 0, 0};
    if (rowA < nrows) {
      if (IN_F32) {
        const float* xp = (const float*)Xv + (size_t)rowA * DD + kbase;
        float4 v0 = ((const float4*)xp)[0];
        float4 v1 = ((const float4*)xp)[1];
        a[0] = (short)f2bf(v0.x); a[1] = (short)f2bf(v0.y);
        a[2] = (short)f2bf(v0.z); a[3] = (short)f2bf(v0.w);
        a[4] = (short)f2bf(v1.x); a[5] = (short)f2bf(v1.y);
        a[6] = (short)f2bf(v1.z); a[7] = (short)f2bf(v1.w);
      } else {
        a = *(const short8*)((const unsigned short*)Xv + (size_t)rowA * DD + kbase);
        if (PRE) {
#pragma unroll
          for (int j = 0; j < 8; ++j) {
            float v = bf2f((unsigned short)a[j]);
            v = fmaxf(fmaf(v, scale[kbase + j], shift[kbase + j]), 0.f);
            a[j] = (short)f2bf(v);
          }
        }
      }
    }
#pragma unroll
    for (int t = 0; t < 8; ++t) {
      short8 b = W8[(t * 4 + s) * 64 + lane];
      acc[t] = __builtin_amdgcn_mfma_f32_16x16x32_bf16(a, b, acc[t], 0, 0, 0);
    }
  }

#pragma unroll
  for (int t = 0; t < 8; ++t) {
    int col = t * 16 + n16;
    float bv = bias[col];
    float s_c = 0.f, q_c = 0.f;
#pragma unroll
    for (int r = 0; r < 4; ++r) {
      int row = m0 + quad * 4 + r;
      if (row < nrows) {
        float v = acc[t][r] + bv;
        if (OUT_BF16) Yb[(size_t)row * DD + col] = f2bf(v);
        if (OUT_F32) Yf[(size_t)row * DD + col] = v;
        if (STATS) { s_c += v; q_c += v * v; }
      }
    }
    if (STATS) {
      s_c += __shfl_xor(s_c, 16);
      q_c += __shfl_xor(q_c, 16);
      s_c += __shfl_xor(s_c, 32);
      q_c += __shfl_xor(q_c, 32);
      if (quad == 0) {
        atomicAdd(&red[0][col], s_c);
        atomicAdd(&red[1][col], q_c);
      }
    }
  }
  if (STATS) {
    __syncthreads();
    if (tid < DD) {
      atomicAdd(&stats[tid], red[0][tid]);
      atomicAdd(&stats[DD + tid], red[1][tid]);
    }
  }
}

// ---------------- BN finalize ----------------

__global__ void k_bnfin(const float* __restrict__ stats, const float* __restrict__ gamma,
                        const float* __restrict__ beta, float* __restrict__ scale,
                        float* __restrict__ shift, float* __restrict__ statsz,
                        float inv_n) {
  int d = threadIdx.x;
  if (d < DD) {
    float mu = stats[d] * inv_n;
    float var = stats[DD + d] * inv_n - mu * mu;
    float sc = gamma[d] * rsqrtf(var + BN_EPS);
    scale[d] = sc;
    shift[d] = fmaf(-mu, sc, beta[d]);
    statsz[d] = 0.f;
    statsz[DD + d] = 0.f;
  }
}

// ---------------- stats of a = relu(bn2(z)), z in bf16 ----------------

__global__ __launch_bounds__(256) void k_stats3(const unsigned short* __restrict__ Z,
                                                const float* __restrict__ sc2,
                                                const float* __restrict__ sh2,
                                                float* __restrict__ stats, int n8) {
  __shared__ float red[2][DD];
  int tid = threadIdx.x;
  if (tid < DD) { red[0][tid] = 0.f; red[1][tid] = 0.f; }
  __syncthreads();
  int c8 = tid & 15;
  float sc[8], sh[8];
#pragma unroll
  for (int j = 0; j < 8; ++j) { sc[j] = sc2[c8 * 8 + j]; sh[j] = sh2[c8 * 8 + j]; }
  float s[8] = {0, 0, 0, 0, 0, 0, 0, 0};
  float q[8] = {0, 0, 0, 0, 0, 0, 0, 0};
  for (int idx = blockIdx.x * 256 + tid; idx < n8; idx += gridDim.x * 256) {
    short8 z = ((const short8*)Z)[idx];
#pragma unroll
    for (int j = 0; j < 8; ++j) {
      float a = fmaxf(fmaf(bf2f((unsigned short)z[j]), sc[j], sh[j]), 0.f);
      s[j] += a;
      q[j] += a * a;
    }
  }
#pragma unroll
  for (int j = 0; j < 8; ++j) {
    atomicAdd(&red[0][c8 * 8 + j], s[j]);
    atomicAdd(&red[1][c8 * 8 + j], q[j]);
  }
  __syncthreads();
  if (tid < DD) {
    atomicAdd(&stats[tid], red[0][tid]);
    atomicAdd(&stats[DD + tid], red[1][tid]);
  }
}

// ------- final: h += relu(bn3(relu(bn2(z)))), h fp32 in d_out, refresh bf16 hb ----

__global__ __launch_bounds__(256) void k_final(
    const unsigned short* __restrict__ Z, const float* __restrict__ sc2,
    const float* __restrict__ sh2, const float* __restrict__ sc3,
    const float* __restrict__ sh3, float* __restrict__ H,
    unsigned short* __restrict__ hbout, int n8) {
  int c8 = threadIdx.x & 15;
  float s2[8], h2[8], s3[8], h3[8];
#pragma unroll
  for (int j = 0; j < 8; ++j) {
    s2[j] = sc2[c8 * 8 + j]; h2[j] = sh2[c8 * 8 + j];
    s3[j] = sc3[c8 * 8 + j]; h3[j] = sh3[c8 * 8 + j];
  }
  for (int idx = blockIdx.x * 256 + threadIdx.x; idx < n8; idx += gridDim.x * 256) {
    short8 z = ((const short8*)Z)[idx];
    float4 hv0 = ((const float4*)H)[idx * 2];
    float4 hv1 = ((const float4*)H)[idx * 2 + 1];
    float hv[8] = {hv0.x, hv0.y, hv0.z, hv0.w, hv1.x, hv1.y, hv1.z, hv1.w};
    float o[8];
    short8 ob;
#pragma unroll
    for (int j = 0; j < 8; ++j) {
      float a = fmaxf(fmaf(bf2f((unsigned short)z[j]), s2[j], h2[j]), 0.f);
      o[j] = hv[j] + fmaxf(fmaf(a, s3[j], h3[j]), 0.f);
      ob[j] = (short)f2bf(o[j]);
    }
    float4 o0 = make_float4(o[0], o[1], o[2], o[3]);
    float4 o1 = make_float4(o[4], o[5], o[6], o[7]);
    ((float4*)H)[idx * 2] = o0;
    ((float4*)H)[idx * 2 + 1] = o1;
    *(short8*)(hbout + (size_t)idx * 8) = ob;
  }
}

// ---------------- launch ----------------

extern "C" void kernel_launch(void* const* d_in, const int* in_sizes, int n_in,
                              void* d_out, int out_size, void* d_ws, size_t ws_size,
                              hipStream_t stream) {
  const float* h_in = (const float*)d_in[0];
  const int* src = (const int*)d_in[1];
  const int* dst = (const int*)d_in[2];
  const float* W_emb = (const float*)d_in[3];
  const float* b_emb = (const float*)d_in[4];
  const float* epsv = (const float*)d_in[5];
  const float* W1 = (const float*)d_in[6];
  const float* b1 = (const float*)d_in[7];
  const float* g1 = (const float*)d_in[8];
  const float* be1 = (const float*)d_in[9];
  const float* W2 = (const float*)d_in[10];
  const float* b2 = (const float*)d_in[11];
  const float* ga = (const float*)d_in[12];
  const float* ba = (const float*)d_in[13];
  const float* gl = (const float*)d_in[14];
  const float* bl = (const float*)d_in[15];

  const int Nn = in_sizes[0] / DD;  // 50000
  const int E = in_sizes[1];        // 1600000

  char* ws = (char*)d_ws;
  size_t off = 0;
  auto alloc = [&](size_t bytes) -> void* {
    off = (off + 255) & ~(size_t)255;
    void* p = ws + off;
    off += bytes;
    return p;
  };
  int* perm = (int*)alloc((size_t)E * 4);
  int* row_start = (int*)alloc((size_t)(Nn + 1) * 4);
  int* counts = (int*)alloc((size_t)Nn * 4);
  int* tile_sums = (int*)alloc(256 * 4);
  unsigned short* Wb = (unsigned short*)alloc((size_t)9 * WSTRIDE * 2);
  float* S = (float*)alloc(2 * DD * 4);
  float* scale1 = (float*)alloc(DD * 4);
  float* shift1 = (float*)alloc(DD * 4);
  float* scale2 = (float*)alloc(DD * 4);
  float* shift2 = (float*)alloc(DD * 4);
  float* scale3 = (float*)alloc(DD * 4);
  float* shift3 = (float*)alloc(DD * 4);
  unsigned short* hb = (unsigned short*)alloc((size_t)Nn * DD * 2);  // bf16 h mirror
  unsigned short* xb = (unsigned short*)alloc((size_t)Nn * DD * 2);  // aggregate out / z
  unsigned short* yb = (unsigned short*)alloc((size_t)Nn * DD * 2);  // gemm1 out
  float* h = (float*)d_out;  // fp32 h chain lives in d_out; final h IS the output

  hipMemsetAsync(counts, 0, (size_t)Nn * 4, stream);
  hipMemsetAsync(S, 0, 2 * DD * 4, stream);

  // CSR build
  int eb = (E + 255) / 256;
  int ntiles = (Nn + 255) / 256;
  k_count<<<eb, 256, 0, stream>>>(dst, counts, E);
  k_scan_tiles<<<ntiles, 256, 0, stream>>>(counts, row_start, tile_sums, Nn);
  k_scan_sums<<<1, 256, 0, stream>>>(tile_sums, ntiles);
  k_scan_add<<<ntiles, 256, 0, stream>>>(row_start, tile_sums, Nn, E);
  k_fill<<<eb, 256, 0, stream>>>(src, dst, row_start, counts, perm, E);

  // W pre-pack (bf16, B-fragment order), 16384 elems per matrix
  k_packW<<<(1 * WSTRIDE + 255) / 256, 256, 0, stream>>>(W_emb, Wb, 1);
  k_packW<<<(4 * WSTRIDE + 255) / 256, 256, 0, stream>>>(W1, Wb + WSTRIDE, 4);
  k_packW<<<(4 * WSTRIDE + 255) / 256, 256, 0, stream>>>(W2, Wb + (size_t)WSTRIDE * 5, 4);

  int gb = (Nn + 63) / 64;
  // embed: h = h_in @ W_emb + b_emb  (fp32 h into d_out + bf16 mirror hb)
  k_gemm_mfma<false, false, true, true, true>
      <<<gb, 256, 0, stream>>>(h_in, Wb, b_emb, nullptr, nullptr, hb, h, nullptr, Nn);

  int n8 = Nn * DD / 8;
  float inv_n = 1.0f / (float)Nn;
  for (int i = 0; i < NL; ++i) {
    k_aggregate<<<(Nn + 3) / 4, 256, 0, stream>>>(hb, row_start, perm, epsv, i, xb, Nn);
    k_gemm_mfma<false, true, false, true, false><<<gb, 256, 0, stream>>>(
        xb, Wb + (size_t)WSTRIDE * (1 + i), b1 + i * DD, nullptr, nullptr, yb, nullptr, S, Nn);
    k_bnfin<<<1, DD, 0, stream>>>(S, g1 + i * DD, be1 + i * DD, scale1, shift1, S, inv_n);
    // GEMM2: reads yb (PRE=bn1+relu), writes z (bf16) into xb
    k_gemm_mfma<true, true, false, true, false><<<gb, 256, 0, stream>>>(
        yb, Wb + (size_t)WSTRIDE * (5 + i), b2 + i * DD, scale1, shift1, xb, nullptr, S, Nn);
    k_bnfin<<<1, DD, 0, stream>>>(S, ga + i * DD, ba + i * DD, scale2, shift2, S, inv_n);
    k_stats3<<<2048, 256, 0, stream>>>(xb, scale2, shift2, S, n8);
    k_bnfin<<<1, DD, 0, stream>>>(S, gl + i * DD, bl + i * DD, scale3, shift3, S, inv_n);
    k_final<<<2048, 256, 0, stream>>>(xb, scale2, shift2, scale3, shift3, h, hb, n8);
  }
}

// Round 5
// 956.405 us; speedup vs baseline: 1.4783x; 1.1622x over previous
//
#include <hip/hip_runtime.h>

#define DD 128
#define NL 4
#define BN_EPS 1e-5f
#define WSTRIDE 16384   // 128*128 bf16 elements per packed matrix
#define CAP 10240       // per-bucket edge capacity (mean 8192, +22 sigma)
#define CHUNK 8192      // edges per k_scatter block

typedef __attribute__((ext_vector_type(8))) short short8;
typedef __attribute__((ext_vector_type(4))) float f32x4;

__device__ inline float bf2f(unsigned short u) {
  unsigned int x = ((unsigned int)u) << 16;
  return __builtin_bit_cast(float, x);
}
__device__ inline unsigned short f2bf(float f) {
  unsigned int u = __builtin_bit_cast(unsigned int, f);
  unsigned int r = (u + 0x7fffu + ((u >> 16) & 1u)) >> 16;
  return (unsigned short)r;
}

// ---------------- bucketed CSR build ----------------
// Pass 1: bin edges into 256-node buckets. Per-(block,bucket) bulk reservation
// keeps each written line block-private -> no partial-line HBM writebacks.

__global__ __launch_bounds__(256) void k_scatter(const int* __restrict__ src,
                                                 const int* __restrict__ dst,
                                                 int* __restrict__ fill,
                                                 int* __restrict__ ebuf, int E) {
  __shared__ int hist[256], blkbase[256], cnt2[256];
  int tid = threadIdx.x;
  hist[tid] = 0;
  cnt2[tid] = 0;
  __syncthreads();
  int base = blockIdx.x * CHUNK;
  int cnt = min(CHUNK, E - base);
  for (int i = tid; i < cnt; i += 256) atomicAdd(&hist[dst[base + i] >> 8], 1);
  __syncthreads();
  int h = hist[tid];
  if (h > 0) blkbase[tid] = atomicAdd(&fill[tid], h);
  __syncthreads();
  for (int i = tid; i < cnt; i += 256) {
    int d = dst[base + i];
    int b = d >> 8;
    int off = blkbase[b] + atomicAdd(&cnt2[b], 1);
    if (off < CAP) ebuf[b * CAP + off] = ((d & 255) << 16) | src[base + i];
  }
}

// Pass 2: per bucket, per-node counts + scan -> row_beg/row_end + perm (ushort).

__global__ __launch_bounds__(256) void k_csr(const int* __restrict__ fill,
                                             const int* __restrict__ ebuf,
                                             unsigned short* __restrict__ perm,
                                             int* __restrict__ row_beg,
                                             int* __restrict__ row_end, int n) {
  __shared__ int ncnt[256], lstart[256], cnt2[256], s[256];
  int tid = threadIdx.x;
  int b = blockIdx.x;
  ncnt[tid] = 0;
  cnt2[tid] = 0;
  __syncthreads();
  int cnt = min(fill[b], CAP);
  int base = b * CAP;
  for (int i = tid; i < cnt; i += 256) atomicAdd(&ncnt[ebuf[base + i] >> 16], 1);
  __syncthreads();
  int v = ncnt[tid];
  s[tid] = v;
  __syncthreads();
  for (int off = 1; off < 256; off <<= 1) {
    int x = (tid >= off) ? s[tid - off] : 0;
    __syncthreads();
    s[tid] += x;
    __syncthreads();
  }
  int st = s[tid] - v;  // exclusive scan
  lstart[tid] = st;
  int node = b * 256 + tid;
  if (node < n) {
    row_beg[node] = base + st;
    row_end[node] = base + st + v;
  }
  __syncthreads();
  for (int i = tid; i < cnt; i += 256) {
    int e = ebuf[base + i];
    int l = e >> 16;
    int pos = lstart[l] + atomicAdd(&cnt2[l], 1);
    perm[base + pos] = (unsigned short)(e & 0xFFFF);
  }
}

// ---------------- W pre-pack: fp32 [nmat,128,128] -> bf16 B-fragment order ------
// 32 fragments/matrix: frag=(t*4+s). lane l, elem j holds
// W[k = s*32 + (l>>4)*8 + j][n = t*16 + (l&15)]

__global__ void k_packW(const float* __restrict__ W, unsigned short* __restrict__ out,
                        int nmat) {
  int idx = blockIdx.x * 256 + threadIdx.x;
  int m = idx >> 14;
  if (m >= nmat) return;
  int o = idx & (WSTRIDE - 1);
  int frag = o >> 9;
  int l = (o >> 3) & 63;
  int j = o & 7;
  int t = frag >> 2, s = frag & 3;
  int k = s * 32 + ((l >> 4) << 3) + j;
  int n = (t << 4) + (l & 15);
  out[(size_t)m * WSTRIDE + o] = f2bf(W[(size_t)m * (DD * DD) + k * DD + n]);
}

// ---------------- GIN aggregation (pull, bucketed CSR, bf16 rows) ----------------

__global__ __launch_bounds__(256) void k_aggregate(
    const unsigned short* __restrict__ hb, const int* __restrict__ row_beg,
    const int* __restrict__ row_end, const unsigned short* __restrict__ perm,
    const float* __restrict__ epsv, int layer, unsigned short* __restrict__ xout,
    int n) {
  int wv = (blockIdx.x * 256 + threadIdx.x) >> 6;
  if (wv >= n) return;
  int lane = threadIdx.x & 63;
  int sub = lane >> 4;  // which of 4 concurrent edges
  int c8 = lane & 15;   // which 8-col chunk of the row
  int beg = row_beg[wv], end = row_end[wv];
  float acc[8] = {0.f, 0.f, 0.f, 0.f, 0.f, 0.f, 0.f, 0.f};
  for (int e = beg + sub; e < end; e += 4) {
    int s = perm[e];
    short8 v = *(const short8*)(hb + (size_t)s * DD + c8 * 8);
#pragma unroll
    for (int j = 0; j < 8; ++j) acc[j] += bf2f((unsigned short)v[j]);
  }
#pragma unroll
  for (int j = 0; j < 8; ++j) {
    acc[j] += __shfl_xor(acc[j], 16);
    acc[j] += __shfl_xor(acc[j], 32);
  }
  if (sub == 0) {
    float ep = 1.0f + epsv[layer];
    short8 hv = *(const short8*)(hb + (size_t)wv * DD + c8 * 8);
    short8 o;
#pragma unroll
    for (int j = 0; j < 8; ++j)
      o[j] = (short)f2bf(fmaf(ep, bf2f((unsigned short)hv[j]), acc[j]));
    *(short8*)(xout + (size_t)wv * DD + c8 * 8) = o;
  }
}

// ---------------- bf16 MFMA GEMM [nrows,128] x [128,128] + bias ----------------
// PRE: relu(x*sc+sh) on A-load; sc/sh derived in-prologue from statsPre+gamma+beta.
// STATS: column sum/sumsq of fp32 output into statsOut[0..127],[128..255].

template <bool PRE, bool STATS, bool IN_F32, bool OUT_BF16, bool OUT_F32>
__global__ __launch_bounds__(256) void k_gemm_mfma(
    const void* __restrict__ Xv, const unsigned short* __restrict__ Wb,
    const float* __restrict__ bias, const float* __restrict__ statsPre,
    const float* __restrict__ gPre, const float* __restrict__ bPre,
    unsigned short* __restrict__ Yb, float* __restrict__ Yf,
    float* __restrict__ statsOut, int nrows, float inv_n) {
  __shared__ float red[2][DD];
  __shared__ float s_sc[DD], s_sh[DD];
  int tid = threadIdx.x;
  int wave = tid >> 6, lane = tid & 63;
  int quad = lane >> 4, n16 = lane & 15;
  int m0 = blockIdx.x * 64 + wave * 16;
  int rowA = m0 + n16;

  if (PRE || STATS) {
    if (tid < DD) {
      if (STATS) { red[0][tid] = 0.f; red[1][tid] = 0.f; }
      if (PRE) {
        float mu = statsPre[tid] * inv_n;
        float var = statsPre[DD + tid] * inv_n - mu * mu;
        float sc = gPre[tid] * rsqrtf(var + BN_EPS);
        s_sc[tid] = sc;
        s_sh[tid] = fmaf(-mu, sc, bPre[tid]);
      }
    }
    __syncthreads();
  }

  f32x4 acc[8];
#pragma unroll
  for (int t = 0; t < 8; ++t) acc[t] = (f32x4){0.f, 0.f, 0.f, 0.f};

  const short8* W8 = (const short8*)Wb;
#pragma unroll
  for (int s = 0; s < 4; ++s) {
    int kbase = s * 32 + quad * 8;
    short8 a = {0, 0, 0, 0, 0, 0, 0, 0};
    if (rowA < nrows) {
      if (IN_F32) {
        const float* xp = (const float*)Xv + (size_t)rowA * DD + kbase;
        float4 v0 = ((const float4*)xp)[0];
        float4 v1 = ((const float4*)xp)[1];
        a[0] = (short)f2bf(v0.x); a[1] = (short)f2bf(v0.y);
        a[2] = (short)f2bf(v0.z); a[3] = (short)f2bf(v0.w);
        a[4] = (short)f2bf(v1.x); a[5] = (short)f2bf(v1.y);
        a[6] = (short)f2bf(v1.z); a[7] = (short)f2bf(v1.w);
      } else {
        a = *(const short8*)((const unsigned short*)Xv + (size_t)rowA * DD + kbase);
        if (PRE) {
#pragma unroll
          for (int j = 0; j < 8; ++j) {
            float v = bf2f((unsigned short)a[j]);
            v = fmaxf(fmaf(v, s_sc[kbase + j], s_sh[kbase + j]), 0.f);
            a[j] = (short)f2bf(v);
          }
        }
      }
    }
#pragma unroll
    for (int t = 0; t < 8; ++t) {
      short8 b = W8[(t * 4 + s) * 64 + lane];
      acc[t] = __builtin_amdgcn_mfma_f32_16x16x32_bf16(a, b, acc[t], 0, 0, 0);
    }
  }

#pragma unroll
  for (int t = 0; t < 8; ++t) {
    int col = t * 16 + n16;
    float bv = bias[col];
    float s_c = 0.f, q_c = 0.f;
#pragma unroll
    for (int r = 0; r < 4; ++r) {
      int row = m0 + quad * 4 + r;
      if (row < nrows) {
        float v = acc[t][r] + bv;
        if (OUT_BF16) Yb[(size_t)row * DD + col] = f2bf(v);
        if (OUT_F32) Yf[(size_t)row * DD + col] = v;
        if (STATS) { s_c += v; q_c += v * v; }
      }
    }
    if (STATS) {
      s_c += __shfl_xor(s_c, 16);
      q_c += __shfl_xor(q_c, 16);
      s_c += __shfl_xor(s_c, 32);
      q_c += __shfl_xor(q_c, 32);
      if (quad == 0) {
        atomicAdd(&red[0][col], s_c);
        atomicAdd(&red[1][col], q_c);
      }
    }
  }
  if (STATS) {
    __syncthreads();
    if (tid < DD) {
      atomicAdd(&statsOut[tid], red[0][tid]);
      atomicAdd(&statsOut[DD + tid], red[1][tid]);
    }
  }
}

// ------- stats of a = relu(bn2(z)), z bf16; bn2 params derived in-prologue -------

__global__ __launch_bounds__(256) void k_stats3(const unsigned short* __restrict__ Z,
                                                const float* __restrict__ stats2,
                                                const float* __restrict__ g2,
                                                const float* __restrict__ b2v,
                                                float* __restrict__ statsOut, int n8,
                                                float inv_n) {
  __shared__ float red[2][DD];
  __shared__ float s_sc[DD], s_sh[DD];
  int tid = threadIdx.x;
  if (tid < DD) {
    red[0][tid] = 0.f;
    red[1][tid] = 0.f;
    float mu = stats2[tid] * inv_n;
    float var = stats2[DD + tid] * inv_n - mu * mu;
    float sc = g2[tid] * rsqrtf(var + BN_EPS);
    s_sc[tid] = sc;
    s_sh[tid] = fmaf(-mu, sc, b2v[tid]);
  }
  __syncthreads();
  int c8 = tid & 15;
  float sc[8], sh[8];
#pragma unroll
  for (int j = 0; j < 8; ++j) { sc[j] = s_sc[c8 * 8 + j]; sh[j] = s_sh[c8 * 8 + j]; }
  float s[8] = {0, 0, 0, 0, 0, 0, 0, 0};
  float q[8] = {0, 0, 0, 0, 0, 0, 0, 0};
  for (int idx = blockIdx.x * 256 + tid; idx < n8; idx += gridDim.x * 256) {
    short8 z = ((const short8*)Z)[idx];
#pragma unroll
    for (int j = 0; j < 8; ++j) {
      float a = fmaxf(fmaf(bf2f((unsigned short)z[j]), sc[j], sh[j]), 0.f);
      s[j] += a;
      q[j] += a * a;
    }
  }
#pragma unroll
  for (int j = 0; j < 8; ++j) {
    atomicAdd(&red[0][c8 * 8 + j], s[j]);
    atomicAdd(&red[1][c8 * 8 + j], q[j]);
  }
  __syncthreads();
  if (tid < DD) {
    atomicAdd(&statsOut[tid], red[0][tid]);
    atomicAdd(&statsOut[DD + tid], red[1][tid]);
  }
}

// ------- final: h += relu(bn3(relu(bn2(z)))); both BN params in-prologue -------

__global__ __launch_bounds__(256) void k_final(
    const unsigned short* __restrict__ Z, const float* __restrict__ stats2,
    const float* __restrict__ g2, const float* __restrict__ b2v,
    const float* __restrict__ stats3, const float* __restrict__ g3,
    const float* __restrict__ b3v, float* __restrict__ H,
    unsigned short* __restrict__ hbout, int n8, float inv_n) {
  __shared__ float s2l[DD], h2l[DD], s3l[DD], h3l[DD];
  int tid = threadIdx.x;
  if (tid < DD) {
    float mu = stats2[tid] * inv_n;
    float var = stats2[DD + tid] * inv_n - mu * mu;
    float sc = g2[tid] * rsqrtf(var + BN_EPS);
    s2l[tid] = sc;
    h2l[tid] = fmaf(-mu, sc, b2v[tid]);
    mu = stats3[tid] * inv_n;
    var = stats3[DD + tid] * inv_n - mu * mu;
    sc = g3[tid] * rsqrtf(var + BN_EPS);
    s3l[tid] = sc;
    h3l[tid] = fmaf(-mu, sc, b3v[tid]);
  }
  __syncthreads();
  int c8 = tid & 15;
  float s2[8], h2[8], s3[8], h3[8];
#pragma unroll
  for (int j = 0; j < 8; ++j) {
    s2[j] = s2l[c8 * 8 + j]; h2[j] = h2l[c8 * 8 + j];
    s3[j] = s3l[c8 * 8 + j]; h3[j] = h3l[c8 * 8 + j];
  }
  for (int idx = blockIdx.x * 256 + tid; idx < n8; idx += gridDim.x * 256) {
    short8 z = ((const short8*)Z)[idx];
    float4 hv0 = ((const float4*)H)[idx * 2];
    float4 hv1 = ((const float4*)H)[idx * 2 + 1];
    float hv[8] = {hv0.x, hv0.y, hv0.z, hv0.w, hv1.x, hv1.y, hv1.z, hv1.w};
    float o[8];
    short8 ob;
#pragma unroll
    for (int j = 0; j < 8; ++j) {
      float a = fmaxf(fmaf(bf2f((unsigned short)z[j]), s2[j], h2[j]), 0.f);
      o[j] = hv[j] + fmaxf(fmaf(a, s3[j], h3[j]), 0.f);
      ob[j] = (short)f2bf(o[j]);
    }
    ((float4*)H)[idx * 2] = make_float4(o[0], o[1], o[2], o[3]);
    ((float4*)H)[idx * 2 + 1] = make_float4(o[4], o[5], o[6], o[7]);
    *(short8*)(hbout + (size_t)idx * 8) = ob;
  }
}

// ---------------- launch ----------------

extern "C" void kernel_launch(void* const* d_in, const int* in_sizes, int n_in,
                              void* d_out, int out_size, void* d_ws, size_t ws_size,
                              hipStream_t stream) {
  const float* h_in = (const float*)d_in[0];
  const int* src = (const int*)d_in[1];
  const int* dst = (const int*)d_in[2];
  const float* W_emb = (const float*)d_in[3];
  const float* b_emb = (const float*)d_in[4];
  const float* epsv = (const float*)d_in[5];
  const float* W1 = (const float*)d_in[6];
  const float* b1 = (const float*)d_in[7];
  const float* g1 = (const float*)d_in[8];
  const float* be1 = (const float*)d_in[9];
  const float* W2 = (const float*)d_in[10];
  const float* b2 = (const float*)d_in[11];
  const float* ga = (const float*)d_in[12];
  const float* ba = (const float*)d_in[13];
  const float* gl = (const float*)d_in[14];
  const float* bl = (const float*)d_in[15];

  const int Nn = in_sizes[0] / DD;  // 50000
  const int E = in_sizes[1];        // 1600000
  const int nbuck = (Nn + 255) >> 8;

  char* ws = (char*)d_ws;
  size_t off = 0;
  auto alloc = [&](size_t bytes) -> void* {
    off = (off + 255) & ~(size_t)255;
    void* p = ws + off;
    off += bytes;
    return p;
  };
  int* ebuf = (int*)alloc((size_t)nbuck * CAP * 4);
  unsigned short* perm = (unsigned short*)alloc((size_t)nbuck * CAP * 2);
  int* fill = (int*)alloc(256 * 4);
  int* row_beg = (int*)alloc((size_t)Nn * 4);
  int* row_end = (int*)alloc((size_t)Nn * 4);
  unsigned short* Wb = (unsigned short*)alloc((size_t)9 * WSTRIDE * 2);
  float* Sall = (float*)alloc((size_t)12 * 2 * DD * 4);  // [layer][stage] stats
  unsigned short* hb = (unsigned short*)alloc((size_t)Nn * DD * 2);
  unsigned short* xb = (unsigned short*)alloc((size_t)Nn * DD * 2);
  unsigned short* yb = (unsigned short*)alloc((size_t)Nn * DD * 2);
  float* h = (float*)d_out;  // fp32 h chain lives in d_out

  hipMemsetAsync(fill, 0, 256 * 4, stream);
  hipMemsetAsync(Sall, 0, (size_t)12 * 2 * DD * 4, stream);

  // CSR build (bucketed)
  int nblk1 = (E + CHUNK - 1) / CHUNK;
  k_scatter<<<nblk1, 256, 0, stream>>>(src, dst, fill, ebuf, E);
  k_csr<<<nbuck, 256, 0, stream>>>(fill, ebuf, perm, row_beg, row_end, Nn);

  // W pre-pack (bf16, B-fragment order)
  k_packW<<<(1 * WSTRIDE + 255) / 256, 256, 0, stream>>>(W_emb, Wb, 1);
  k_packW<<<(4 * WSTRIDE + 255) / 256, 256, 0, stream>>>(W1, Wb + WSTRIDE, 4);
  k_packW<<<(4 * WSTRIDE + 255) / 256, 256, 0, stream>>>(W2, Wb + (size_t)WSTRIDE * 5, 4);

  int gb = (Nn + 63) / 64;
  float inv_n = 1.0f / (float)Nn;
  int n8 = Nn * DD / 8;

  // embed: h = h_in @ W_emb + b_emb (fp32 h into d_out + bf16 mirror hb)
  k_gemm_mfma<false, false, true, true, true><<<gb, 256, 0, stream>>>(
      h_in, Wb, b_emb, nullptr, nullptr, nullptr, hb, h, nullptr, Nn, inv_n);

  for (int i = 0; i < NL; ++i) {
    float* S1 = Sall + (size_t)(i * 3 + 0) * 2 * DD;
    float* S2 = Sall + (size_t)(i * 3 + 1) * 2 * DD;
    float* S3 = Sall + (size_t)(i * 3 + 2) * 2 * DD;
    k_aggregate<<<(Nn + 3) / 4, 256, 0, stream>>>(hb, row_beg, row_end, perm, epsv, i,
                                                  xb, Nn);
    k_gemm_mfma<false, true, false, true, false><<<gb, 256, 0, stream>>>(
        xb, Wb + (size_t)WSTRIDE * (1 + i), b1 + i * DD, nullptr, nullptr, nullptr,
        yb, nullptr, S1, Nn, inv_n);
    k_gemm_mfma<true, true, false, true, false><<<gb, 256, 0, stream>>>(
        yb, Wb + (size_t)WSTRIDE * (5 + i), b2 + i * DD, S1, g1 + i * DD, be1 + i * DD,
        xb, nullptr, S2, Nn, inv_n);
    k_stats3<<<2048, 256, 0, stream>>>(xb, S2, ga + i * DD, ba + i * DD, S3, n8, inv_n);
    k_final<<<2048, 256, 0, stream>>>(xb, S2, ga + i * DD, ba + i * DD, S3, gl + i * DD,
                                      bl + i * DD, h, hb, n8, inv_n);
  }
}

// Round 6
// 692.343 us; speedup vs baseline: 2.0421x; 1.3814x over previous
//
#include <hip/hip_runtime.h>

#define DD 128
#define NL 4
#define BN_EPS 1e-5f
#define WSTRIDE 16384   // 128*128 bf16 elements per packed matrix
#define CAP 10240       // per-bucket edge capacity
#define CHUNK 8192      // edges per k_scatter block
#define NST 512         // k_stats3 grid

typedef __attribute__((ext_vector_type(8))) short short8;
typedef __attribute__((ext_vector_type(4))) float f32x4;

__device__ inline float bf2f(unsigned short u) {
  unsigned int x = ((unsigned int)u) << 16;
  return __builtin_bit_cast(float, x);
}
__device__ inline unsigned short f2bf(float f) {
  unsigned int u = __builtin_bit_cast(unsigned int, f);
  unsigned int r = (u + 0x7fffu + ((u >> 16) & 1u)) >> 16;
  return (unsigned short)r;
}

// ---------------- bucketed CSR build ----------------

__global__ __launch_bounds__(256) void k_scatter(const int* __restrict__ src,
                                                 const int* __restrict__ dst,
                                                 int* __restrict__ fill,
                                                 int* __restrict__ ebuf, int E) {
  __shared__ int hist[256], blkbase[256], cnt2[256];
  int tid = threadIdx.x;
  hist[tid] = 0;
  cnt2[tid] = 0;
  __syncthreads();
  int base = blockIdx.x * CHUNK;
  int cnt = min(CHUNK, E - base);
  for (int i = tid; i < cnt; i += 256) atomicAdd(&hist[dst[base + i] >> 8], 1);
  __syncthreads();
  int h = hist[tid];
  if (h > 0) blkbase[tid] = atomicAdd(&fill[tid], h);
  __syncthreads();
  for (int i = tid; i < cnt; i += 256) {
    int d = dst[base + i];
    int b = d >> 8;
    int off = blkbase[b] + atomicAdd(&cnt2[b], 1);
    if (off < CAP) ebuf[b * CAP + off] = ((d & 255) << 16) | src[base + i];
  }
}

__global__ __launch_bounds__(256) void k_csr(const int* __restrict__ fill,
                                             const int* __restrict__ ebuf,
                                             unsigned short* __restrict__ perm,
                                             int* __restrict__ row_beg,
                                             int* __restrict__ row_end, int n) {
  __shared__ int ncnt[256], lstart[256], cnt2[256], s[256];
  int tid = threadIdx.x;
  int b = blockIdx.x;
  ncnt[tid] = 0;
  cnt2[tid] = 0;
  __syncthreads();
  int cnt = min(fill[b], CAP);
  int base = b * CAP;
  for (int i = tid; i < cnt; i += 256) atomicAdd(&ncnt[ebuf[base + i] >> 16], 1);
  __syncthreads();
  int v = ncnt[tid];
  s[tid] = v;
  __syncthreads();
  for (int off = 1; off < 256; off <<= 1) {
    int x = (tid >= off) ? s[tid - off] : 0;
    __syncthreads();
    s[tid] += x;
    __syncthreads();
  }
  int st = s[tid] - v;
  lstart[tid] = st;
  int node = b * 256 + tid;
  if (node < n) {
    row_beg[node] = base + st;
    row_end[node] = base + st + v;
  }
  __syncthreads();
  for (int i = tid; i < cnt; i += 256) {
    int e = ebuf[base + i];
    int l = e >> 16;
    int pos = lstart[l] + atomicAdd(&cnt2[l], 1);
    perm[base + pos] = (unsigned short)(e & 0xFFFF);
  }
}

// ---------------- W pre-pack ----------------

__global__ void k_packW(const float* __restrict__ W, unsigned short* __restrict__ out,
                        int nmat) {
  int idx = blockIdx.x * 256 + threadIdx.x;
  int m = idx >> 14;
  if (m >= nmat) return;
  int o = idx & (WSTRIDE - 1);
  int frag = o >> 9;
  int l = (o >> 3) & 63;
  int j = o & 7;
  int t = frag >> 2, s = frag & 3;
  int k = s * 32 + ((l >> 4) << 3) + j;
  int n = (t << 4) + (l & 15);
  out[(size_t)m * WSTRIDE + o] = f2bf(W[(size_t)m * (DD * DD) + k * DD + n]);
}

// ---------------- stats partial reduce: Spart[nblk][256] -> S[256] ----------------
// grid 32 x 256: block handles 8 entries

__global__ __launch_bounds__(256) void k_reduce(const float* __restrict__ Spart,
                                                float* __restrict__ S, int nblk) {
  __shared__ float red[256];
  int tid = threadIdx.x;
  int jj = tid & 7;
  int r = tid >> 3;  // 0..31
  int j = blockIdx.x * 8 + jj;
  float acc = 0.f;
  for (int i = r; i < nblk; i += 32) acc += Spart[(size_t)i * 256 + j];
  red[tid] = acc;
  __syncthreads();
  if (tid < 8) {
    float t = 0.f;
    for (int i = 0; i < 32; ++i) t += red[i * 8 + tid];
    S[blockIdx.x * 8 + tid] = t;
  }
}

// ---------------- GIN aggregation (pull, bucketed CSR, bf16 rows) ----------------

__global__ __launch_bounds__(256) void k_aggregate(
    const unsigned short* __restrict__ hb, const int* __restrict__ row_beg,
    const int* __restrict__ row_end, const unsigned short* __restrict__ perm,
    const float* __restrict__ epsv, int layer, unsigned short* __restrict__ xout,
    int n) {
  int wv = (blockIdx.x * 256 + threadIdx.x) >> 6;
  if (wv >= n) return;
  int lane = threadIdx.x & 63;
  int sub = lane >> 4;
  int c8 = lane & 15;
  int beg = row_beg[wv], end = row_end[wv];
  float acc[8] = {0.f, 0.f, 0.f, 0.f, 0.f, 0.f, 0.f, 0.f};
  for (int e = beg + sub; e < end; e += 4) {
    int s = perm[e];
    short8 v = *(const short8*)(hb + (size_t)s * DD + c8 * 8);
#pragma unroll
    for (int j = 0; j < 8; ++j) acc[j] += bf2f((unsigned short)v[j]);
  }
#pragma unroll
  for (int j = 0; j < 8; ++j) {
    acc[j] += __shfl_xor(acc[j], 16);
    acc[j] += __shfl_xor(acc[j], 32);
  }
  if (sub == 0) {
    float ep = 1.0f + epsv[layer];
    short8 hv = *(const short8*)(hb + (size_t)wv * DD + c8 * 8);
    short8 o;
#pragma unroll
    for (int j = 0; j < 8; ++j)
      o[j] = (short)f2bf(fmaf(ep, bf2f((unsigned short)hv[j]), acc[j]));
    *(short8*)(xout + (size_t)wv * DD + c8 * 8) = o;
  }
}

// ---------------- bf16 MFMA GEMM [nrows,128] x [128,128] + bias ----------------
// PRE: relu(x*sc+sh) on A-load, params derived in-prologue from S (finalized stats).
// STATS: per-block column sum/sumsq written NON-ATOMICALLY to Spart[bid][256].

template <bool PRE, bool STATS, bool IN_F32, bool OUT_BF16, bool OUT_F32>
__global__ __launch_bounds__(256) void k_gemm_mfma(
    const void* __restrict__ Xv, const unsigned short* __restrict__ Wb,
    const float* __restrict__ bias, const float* __restrict__ statsPre,
    const float* __restrict__ gPre, const float* __restrict__ bPre,
    unsigned short* __restrict__ Yb, float* __restrict__ Yf,
    float* __restrict__ Spart, int nrows, float inv_n) {
  __shared__ float red[4][2][DD];  // [wave][sum/sumsq][col]
  __shared__ float s_sc[DD], s_sh[DD];
  int tid = threadIdx.x;
  int wave = tid >> 6, lane = tid & 63;
  int quad = lane >> 4, n16 = lane & 15;
  int m0 = blockIdx.x * 64 + wave * 16;
  int rowA = m0 + n16;

  if (PRE) {
    if (tid < DD) {
      float mu = statsPre[tid] * inv_n;
      float var = statsPre[DD + tid] * inv_n - mu * mu;
      float sc = gPre[tid] * rsqrtf(var + BN_EPS);
      s_sc[tid] = sc;
      s_sh[tid] = fmaf(-mu, sc, bPre[tid]);
    }
    __syncthreads();
  }

  f32x4 acc[8];
#pragma unroll
  for (int t = 0; t < 8; ++t) acc[t] = (f32x4){0.f, 0.f, 0.f, 0.f};

  const short8* W8 = (const short8*)Wb;
#pragma unroll
  for (int s = 0; s < 4; ++s) {
    int kbase = s * 32 + quad * 8;
    short8 a = {0, 0, 0, 0, 0, 0, 0, 0};
    if (rowA < nrows) {
      if (IN_F32) {
        const float* xp = (const float*)Xv + (size_t)rowA * DD + kbase;
        float4 v0 = ((const float4*)xp)[0];
        float4 v1 = ((const float4*)xp)[1];
        a[0] = (short)f2bf(v0.x); a[1] = (short)f2bf(v0.y);
        a[2] = (short)f2bf(v0.z); a[3] = (short)f2bf(v0.w);
        a[4] = (short)f2bf(v1.x); a[5] = (short)f2bf(v1.y);
        a[6] = (short)f2bf(v1.z); a[7] = (short)f2bf(v1.w);
      } else {
        a = *(const short8*)((const unsigned short*)Xv + (size_t)rowA * DD + kbase);
        if (PRE) {
#pragma unroll
          for (int j = 0; j < 8; ++j) {
            float v = bf2f((unsigned short)a[j]);
            v = fmaxf(fmaf(v, s_sc[kbase + j], s_sh[kbase + j]), 0.f);
            a[j] = (short)f2bf(v);
          }
        }
      }
    }
#pragma unroll
    for (int t = 0; t < 8; ++t) {
      short8 b = W8[(t * 4 + s) * 64 + lane];
      acc[t] = __builtin_amdgcn_mfma_f32_16x16x32_bf16(a, b, acc[t], 0, 0, 0);
    }
  }

#pragma unroll
  for (int t = 0; t < 8; ++t) {
    int col = t * 16 + n16;
    float bv = bias[col];
    float s_c = 0.f, q_c = 0.f;
#pragma unroll
    for (int r = 0; r < 4; ++r) {
      int row = m0 + quad * 4 + r;
      if (row < nrows) {
        float v = acc[t][r] + bv;
        if (OUT_BF16) Yb[(size_t)row * DD + col] = f2bf(v);
        if (OUT_F32) Yf[(size_t)row * DD + col] = v;
        if (STATS) { s_c += v; q_c += v * v; }
      }
    }
    if (STATS) {
      s_c += __shfl_xor(s_c, 16);
      q_c += __shfl_xor(q_c, 16);
      s_c += __shfl_xor(s_c, 32);
      q_c += __shfl_xor(q_c, 32);
      if (quad == 0) {  // lanes 0..15: one writer per (wave,col)
        red[wave][0][col] = s_c;
        red[wave][1][col] = q_c;
      }
    }
  }
  if (STATS) {
    __syncthreads();
    if (tid < DD) {
      float s4 = red[0][0][tid] + red[1][0][tid] + red[2][0][tid] + red[3][0][tid];
      float q4 = red[0][1][tid] + red[1][1][tid] + red[2][1][tid] + red[3][1][tid];
      Spart[(size_t)blockIdx.x * 256 + tid] = s4;
      Spart[(size_t)blockIdx.x * 256 + DD + tid] = q4;
    }
  }
}

// ------- stats of a = relu(bn2(z)), z bf16; non-atomic per-block partials -------

__global__ __launch_bounds__(256) void k_stats3(const unsigned short* __restrict__ Z,
                                                const float* __restrict__ stats2,
                                                const float* __restrict__ g2,
                                                const float* __restrict__ b2v,
                                                float* __restrict__ Spart, int n8,
                                                float inv_n) {
  __shared__ float wred[4][2][DD];
  __shared__ float s_sc[DD], s_sh[DD];
  int tid = threadIdx.x;
  if (tid < DD) {
    float mu = stats2[tid] * inv_n;
    float var = stats2[DD + tid] * inv_n - mu * mu;
    float sc = g2[tid] * rsqrtf(var + BN_EPS);
    s_sc[tid] = sc;
    s_sh[tid] = fmaf(-mu, sc, b2v[tid]);
  }
  __syncthreads();
  int c8 = tid & 15;
  int wave = tid >> 6, lane = tid & 63;
  float sc[8], sh[8];
#pragma unroll
  for (int j = 0; j < 8; ++j) { sc[j] = s_sc[c8 * 8 + j]; sh[j] = s_sh[c8 * 8 + j]; }
  float s[8] = {0, 0, 0, 0, 0, 0, 0, 0};
  float q[8] = {0, 0, 0, 0, 0, 0, 0, 0};
  for (int idx = blockIdx.x * 256 + tid; idx < n8; idx += gridDim.x * 256) {
    short8 z = ((const short8*)Z)[idx];
#pragma unroll
    for (int j = 0; j < 8; ++j) {
      float a = fmaxf(fmaf(bf2f((unsigned short)z[j]), sc[j], sh[j]), 0.f);
      s[j] += a;
      q[j] += a * a;
    }
  }
#pragma unroll
  for (int j = 0; j < 8; ++j) {  // combine lanes with equal c8 (xor 16, 32)
    s[j] += __shfl_xor(s[j], 16);
    q[j] += __shfl_xor(q[j], 16);
    s[j] += __shfl_xor(s[j], 32);
    q[j] += __shfl_xor(q[j], 32);
  }
  if (lane < 16) {
#pragma unroll
    for (int j = 0; j < 8; ++j) {
      wred[wave][0][lane * 8 + j] = s[j];
      wred[wave][1][lane * 8 + j] = q[j];
    }
  }
  __syncthreads();
  if (tid < DD) {
    float s4 = wred[0][0][tid] + wred[1][0][tid] + wred[2][0][tid] + wred[3][0][tid];
    float q4 = wred[0][1][tid] + wred[1][1][tid] + wred[2][1][tid] + wred[3][1][tid];
    Spart[(size_t)blockIdx.x * 256 + tid] = s4;
    Spart[(size_t)blockIdx.x * 256 + DD + tid] = q4;
  }
}

// ------- final: h += relu(bn3(relu(bn2(z)))); both BN params in-prologue -------

__global__ __launch_bounds__(256) void k_final(
    const unsigned short* __restrict__ Z, const float* __restrict__ stats2,
    const float* __restrict__ g2, const float* __restrict__ b2v,
    const float* __restrict__ stats3, const float* __restrict__ g3,
    const float* __restrict__ b3v, float* __restrict__ H,
    unsigned short* __restrict__ hbout, int n8, float inv_n) {
  __shared__ float s2l[DD], h2l[DD], s3l[DD], h3l[DD];
  int tid = threadIdx.x;
  if (tid < DD) {
    float mu = stats2[tid] * inv_n;
    float var = stats2[DD + tid] * inv_n - mu * mu;
    float sc = g2[tid] * rsqrtf(var + BN_EPS);
    s2l[tid] = sc;
    h2l[tid] = fmaf(-mu, sc, b2v[tid]);
    mu = stats3[tid] * inv_n;
    var = stats3[DD + tid] * inv_n - mu * mu;
    sc = g3[tid] * rsqrtf(var + BN_EPS);
    s3l[tid] = sc;
    h3l[tid] = fmaf(-mu, sc, b3v[tid]);
  }
  __syncthreads();
  int c8 = tid & 15;
  float s2[8], h2[8], s3[8], h3[8];
#pragma unroll
  for (int j = 0; j < 8; ++j) {
    s2[j] = s2l[c8 * 8 + j]; h2[j] = h2l[c8 * 8 + j];
    s3[j] = s3l[c8 * 8 + j]; h3[j] = h3l[c8 * 8 + j];
  }
  for (int idx = blockIdx.x * 256 + tid; idx < n8; idx += gridDim.x * 256) {
    short8 z = ((const short8*)Z)[idx];
    float4 hv0 = ((const float4*)H)[idx * 2];
    float4 hv1 = ((const float4*)H)[idx * 2 + 1];
    float hv[8] = {hv0.x, hv0.y, hv0.z, hv0.w, hv1.x, hv1.y, hv1.z, hv1.w};
    float o[8];
    short8 ob;
#pragma unroll
    for (int j = 0; j < 8; ++j) {
      float a = fmaxf(fmaf(bf2f((unsigned short)z[j]), s2[j], h2[j]), 0.f);
      o[j] = hv[j] + fmaxf(fmaf(a, s3[j], h3[j]), 0.f);
      ob[j] = (short)f2bf(o[j]);
    }
    ((float4*)H)[idx * 2] = make_float4(o[0], o[1], o[2], o[3]);
    ((float4*)H)[idx * 2 + 1] = make_float4(o[4], o[5], o[6], o[7]);
    *(short8*)(hbout + (size_t)idx * 8) = ob;
  }
}

// ---------------- launch ----------------

extern "C" void kernel_launch(void* const* d_in, const int* in_sizes, int n_in,
                              void* d_out, int out_size, void* d_ws, size_t ws_size,
                              hipStream_t stream) {
  const float* h_in = (const float*)d_in[0];
  const int* src = (const int*)d_in[1];
  const int* dst = (const int*)d_in[2];
  const float* W_emb = (const float*)d_in[3];
  const float* b_emb = (const float*)d_in[4];
  const float* epsv = (const float*)d_in[5];
  const float* W1 = (const float*)d_in[6];
  const float* b1 = (const float*)d_in[7];
  const float* g1 = (const float*)d_in[8];
  const float* be1 = (const float*)d_in[9];
  const float* W2 = (const float*)d_in[10];
  const float* b2 = (const float*)d_in[11];
  const float* ga = (const float*)d_in[12];
  const float* ba = (const float*)d_in[13];
  const float* gl = (const float*)d_in[14];
  const float* bl = (const float*)d_in[15];

  const int Nn = in_sizes[0] / DD;  // 50000
  const int E = in_sizes[1];        // 1600000
  const int nbuck = (Nn + 255) >> 8;
  const int gb = (Nn + 63) / 64;

  char* ws = (char*)d_ws;
  size_t off = 0;
  auto alloc = [&](size_t bytes) -> void* {
    off = (off + 255) & ~(size_t)255;
    void* p = ws + off;
    off += bytes;
    return p;
  };
  int* ebuf = (int*)alloc((size_t)nbuck * CAP * 4);
  unsigned short* perm = (unsigned short*)alloc((size_t)nbuck * CAP * 2);
  int* fill = (int*)alloc(256 * 4);
  int* row_beg = (int*)alloc((size_t)Nn * 4);
  int* row_end = (int*)alloc((size_t)Nn * 4);
  unsigned short* Wb = (unsigned short*)alloc((size_t)9 * WSTRIDE * 2);
  float* Spart = (float*)alloc((size_t)gb * 256 * 4);   // per-block stat partials
  float* Sfin = (float*)alloc((size_t)3 * 256 * 4);     // S1,S2,S3 (current layer)
  unsigned short* hb = (unsigned short*)alloc((size_t)Nn * DD * 2);
  unsigned short* xb = (unsigned short*)alloc((size_t)Nn * DD * 2);
  unsigned short* yb = (unsigned short*)alloc((size_t)Nn * DD * 2);
  float* h = (float*)d_out;  // fp32 h chain lives in d_out

  hipMemsetAsync(fill, 0, 256 * 4, stream);

  // CSR build (bucketed)
  int nblk1 = (E + CHUNK - 1) / CHUNK;
  k_scatter<<<nblk1, 256, 0, stream>>>(src, dst, fill, ebuf, E);
  k_csr<<<nbuck, 256, 0, stream>>>(fill, ebuf, perm, row_beg, row_end, Nn);

  // W pre-pack (bf16, B-fragment order)
  k_packW<<<(1 * WSTRIDE + 255) / 256, 256, 0, stream>>>(W_emb, Wb, 1);
  k_packW<<<(4 * WSTRIDE + 255) / 256, 256, 0, stream>>>(W1, Wb + WSTRIDE, 4);
  k_packW<<<(4 * WSTRIDE + 255) / 256, 256, 0, stream>>>(W2, Wb + (size_t)WSTRIDE * 5, 4);

  float inv_n = 1.0f / (float)Nn;
  int n8 = Nn * DD / 8;

  // embed: h = h_in @ W_emb + b_emb (fp32 h into d_out + bf16 mirror hb)
  k_gemm_mfma<false, false, true, true, true><<<gb, 256, 0, stream>>>(
      h_in, Wb, b_emb, nullptr, nullptr, nullptr, hb, h, nullptr, Nn, inv_n);

  float* S1 = Sfin;
  float* S2 = Sfin + 256;
  float* S3 = Sfin + 512;
  for (int i = 0; i < NL; ++i) {
    k_aggregate<<<(Nn + 3) / 4, 256, 0, stream>>>(hb, row_beg, row_end, perm, epsv, i,
                                                  xb, Nn);
    k_gemm_mfma<false, true, false, true, false><<<gb, 256, 0, stream>>>(
        xb, Wb + (size_t)WSTRIDE * (1 + i), b1 + i * DD, nullptr, nullptr, nullptr,
        yb, nullptr, Spart, Nn, inv_n);
    k_reduce<<<32, 256, 0, stream>>>(Spart, S1, gb);
    k_gemm_mfma<true, true, false, true, false><<<gb, 256, 0, stream>>>(
        yb, Wb + (size_t)WSTRIDE * (5 + i), b2 + i * DD, S1, g1 + i * DD, be1 + i * DD,
        xb, nullptr, Spart, Nn, inv_n);
    k_reduce<<<32, 256, 0, stream>>>(Spart, S2, gb);
    k_stats3<<<NST, 256, 0, stream>>>(xb, S2, ga + i * DD, ba + i * DD, Spart, n8,
                                      inv_n);
    k_reduce<<<32, 256, 0, stream>>>(Spart, S3, NST);
    k_final<<<2048, 256, 0, stream>>>(xb, S2, ga + i * DD, ba + i * DD, S3, gl + i * DD,
                                      bl + i * DD, h, hb, n8, inv_n);
  }
}